// Round 1
// baseline (572.096 us; speedup 1.0000x reference)
//
#include <hip/hip_runtime.h>
#include <cstdint>
#include <cstddef>

#define N_NODES 100000
#define N_EDGES 1600000
#define IN_CH   128
#define HID_CH  128
#define OUT_CH  64

// ---------------- CSR build ----------------

__global__ void k_zero(int* __restrict__ deg) {
    int i = blockIdx.x * 256 + threadIdx.x;
    if (i < N_NODES) deg[i] = 0;
}

__global__ void k_count(const int* __restrict__ ei, int* __restrict__ deg) {
    int e = blockIdx.x * 256 + threadIdx.x;
    if (e < N_EDGES) atomicAdd(&deg[ei[N_EDGES + e]], 1);
}

// Single-block exclusive scan over deg -> rowptr, plus cursor copy and dinv.
__global__ __launch_bounds__(1024) void k_scan(const int* __restrict__ deg,
                                               int* __restrict__ rowptr,
                                               int* __restrict__ cursor,
                                               float* __restrict__ dinv) {
    __shared__ int wsum[16];
    const int tid  = threadIdx.x;
    const int lane = tid & 63;
    const int wid  = tid >> 6;
    int carry = 0;
    for (int base = 0; base < N_NODES; base += 1024) {
        int i = base + tid;
        int v = (i < N_NODES) ? deg[i] : 0;
        // inclusive scan within wave
        int x = v;
        #pragma unroll
        for (int d = 1; d < 64; d <<= 1) {
            int y = __shfl_up(x, d, 64);
            if (lane >= d) x += y;
        }
        if (lane == 63) wsum[wid] = x;
        __syncthreads();
        if (wid == 0) {
            int ws = (lane < 16) ? wsum[lane] : 0;
            #pragma unroll
            for (int d = 1; d < 16; d <<= 1) {
                int y = __shfl_up(ws, d, 64);
                if (lane >= d) ws += y;
            }
            if (lane < 16) wsum[lane] = ws;
        }
        __syncthreads();
        int waveoff = (wid == 0) ? 0 : wsum[wid - 1];
        int excl = carry + waveoff + (x - v);
        if (i < N_NODES) {
            rowptr[i] = excl;
            cursor[i] = excl;
            dinv[i]   = rsqrtf((float)(v + 1));  // +1 for self-loop
        }
        carry += wsum[15];
        __syncthreads();  // protect wsum before next chunk
    }
    if (tid == 0) rowptr[N_NODES] = carry;
}

__global__ void k_fill(const int* __restrict__ ei, int* __restrict__ cursor,
                       int* __restrict__ srcs) {
    int e = blockIdx.x * 256 + threadIdx.x;
    if (e < N_EDGES) {
        int d = ei[N_EDGES + e];
        int pos = atomicAdd(&cursor[d], 1);
        srcs[pos] = ei[e];
    }
}

// ---------------- GEMM (K=128 fixed) ----------------
// Block of 256 threads computes a 64-row x OC-col tile.
// Thread tile: RPT rows x 4 cols. CG = OC/4 col-groups, RG = 256/CG row-groups.
template <int OC, int RPT>
__global__ __launch_bounds__(256) void k_gemm(const float* __restrict__ A,
                                              const float* __restrict__ W,
                                              float* __restrict__ out,
                                              int nrows) {
    constexpr int CG   = OC / 4;
    constexpr int RG   = 256 / CG;
    constexpr int ROWS = RG * RPT;   // 64
    constexpr int LDSP = 128 + 4;    // pad: row stride 132 floats (528B, 16B-aligned)
    __shared__ float xs[ROWS][LDSP];

    const int tid  = threadIdx.x;
    const int row0 = blockIdx.x * ROWS;

    // stage A tile: ROWS x 128 floats via float4 (coalesced)
    for (int idx = tid; idx < ROWS * 32; idx += 256) {
        int r = idx >> 5, c4 = idx & 31;
        int gr = row0 + r;
        if (gr >= nrows) gr = nrows - 1;
        float4 v = ((const float4*)(A + (size_t)gr * 128))[c4];
        float* dp = &xs[r][c4 * 4];
        dp[0] = v.x; dp[1] = v.y; dp[2] = v.z; dp[3] = v.w;
    }
    __syncthreads();

    const int cg = tid % CG;
    const int rg = tid / CG;

    float acc[RPT][4];
    #pragma unroll
    for (int r = 0; r < RPT; r++) {
        acc[r][0] = acc[r][1] = acc[r][2] = acc[r][3] = 0.f;
    }

    const float* Wp = W + cg * 4;
    for (int k = 0; k < 128; k += 4) {
        float4 w0 = *(const float4*)(Wp + (size_t)(k + 0) * OC);
        float4 w1 = *(const float4*)(Wp + (size_t)(k + 1) * OC);
        float4 w2 = *(const float4*)(Wp + (size_t)(k + 2) * OC);
        float4 w3 = *(const float4*)(Wp + (size_t)(k + 3) * OC);
        #pragma unroll
        for (int r = 0; r < RPT; r++) {
            float4 xv = *(const float4*)&xs[rg * RPT + r][k];
            acc[r][0] = fmaf(xv.w, w3.x, fmaf(xv.z, w2.x, fmaf(xv.y, w1.x, fmaf(xv.x, w0.x, acc[r][0]))));
            acc[r][1] = fmaf(xv.w, w3.y, fmaf(xv.z, w2.y, fmaf(xv.y, w1.y, fmaf(xv.x, w0.y, acc[r][1]))));
            acc[r][2] = fmaf(xv.w, w3.z, fmaf(xv.z, w2.z, fmaf(xv.y, w1.z, fmaf(xv.x, w0.z, acc[r][2]))));
            acc[r][3] = fmaf(xv.w, w3.w, fmaf(xv.z, w2.w, fmaf(xv.y, w1.w, fmaf(xv.x, w0.w, acc[r][3]))));
        }
    }

    #pragma unroll
    for (int r = 0; r < RPT; r++) {
        int gr = row0 + rg * RPT + r;
        if (gr < nrows) {
            float4 o = make_float4(acc[r][0], acc[r][1], acc[r][2], acc[r][3]);
            *(float4*)(out + (size_t)gr * OC + cg * 4) = o;
        }
    }
}

// ---------------- Aggregation (pull via CSR) ----------------
// One block per node, CH threads (1 per channel).
template <int CH>
__global__ __launch_bounds__(CH) void k_agg(const float* __restrict__ h,
                                            const int* __restrict__ rowptr,
                                            const int* __restrict__ srcs,
                                            const float* __restrict__ dinv,
                                            const float* __restrict__ bias,
                                            float* __restrict__ out,
                                            int do_relu) {
    const int i   = blockIdx.x;
    const int tid = threadIdx.x;
    __shared__ int   ls[256];
    __shared__ float lw[256];

    const int start = rowptr[i];
    const int end   = rowptr[i + 1];
    const float di  = dinv[i];

    // self-loop contribution: norm = dinv[i]^2
    float acc = h[(size_t)i * CH + tid] * (di * di);

    for (int base = start; base < end; base += 256) {
        int cnt = min(end - base, 256);
        __syncthreads();
        for (int j = tid; j < cnt; j += CH) {
            int s = srcs[base + j];
            ls[j] = s;
            lw[j] = dinv[s] * di;
        }
        __syncthreads();
        for (int j = 0; j < cnt; j++) {
            acc += h[(size_t)ls[j] * CH + tid] * lw[j];
        }
    }

    float o = acc + bias[tid];
    if (do_relu) o = fmaxf(o, 0.f);
    out[(size_t)i * CH + tid] = o;
}

// ---------------- launch ----------------

extern "C" void kernel_launch(void* const* d_in, const int* in_sizes, int n_in,
                              void* d_out, int out_size, void* d_ws, size_t ws_size,
                              hipStream_t stream) {
    const float* x  = (const float*)d_in[0];
    const int*   ei = (const int*)d_in[1];   // [2, E] int32
    const float* W1 = (const float*)d_in[2];
    const float* b1 = (const float*)d_in[3];
    const float* W2 = (const float*)d_in[4];
    const float* b2 = (const float*)d_in[5];
    float* out = (float*)d_out;

    char* p = (char*)d_ws;
    size_t used = 0;
    auto alloc = [&](size_t bytes) {
        void* q = (void*)p;
        size_t pad = (bytes + 255) & ~(size_t)255;
        p += pad;
        used += pad;
        return q;
    };
    int*   deg    = (int*)alloc(sizeof(int) * N_NODES);
    int*   rowptr = (int*)alloc(sizeof(int) * (N_NODES + 1));
    int*   cursor = (int*)alloc(sizeof(int) * N_NODES);
    float* dinv   = (float*)alloc(sizeof(float) * N_NODES);
    int*   srcs   = (int*)alloc(sizeof(int) * N_EDGES);
    float* h1     = (float*)alloc(sizeof(float) * (size_t)N_NODES * HID_CH);
    float* agg1   = (float*)alloc(sizeof(float) * (size_t)N_NODES * HID_CH);
    float* h2     = h1;  // reuse: h1 dead after agg1 is built

    if (used > ws_size) return;  // workspace too small: fail loudly (validation), not by corruption

    k_zero<<<(N_NODES + 255) / 256, 256, 0, stream>>>(deg);
    k_count<<<(N_EDGES + 255) / 256, 256, 0, stream>>>(ei, deg);
    k_scan<<<1, 1024, 0, stream>>>(deg, rowptr, cursor, dinv);
    k_fill<<<(N_EDGES + 255) / 256, 256, 0, stream>>>(ei, cursor, srcs);

    k_gemm<128, 8><<<(N_NODES + 63) / 64, 256, 0, stream>>>(x, W1, h1, N_NODES);
    k_agg<128><<<N_NODES, 128, 0, stream>>>(h1, rowptr, srcs, dinv, b1, agg1, 1);
    k_gemm<64, 4><<<(N_NODES + 63) / 64, 256, 0, stream>>>(agg1, W2, h2, N_NODES);
    k_agg<64><<<N_NODES, 64, 0, stream>>>(h2, rowptr, srcs, dinv, b2, out, 0);
}

// Round 2
// 477.439 us; speedup vs baseline: 1.1983x; 1.1983x over previous
//
#include <hip/hip_runtime.h>
#include <cstdint>
#include <cstddef>

#define N_NODES 100000
#define N_EDGES 1600000
#define IN_CH   128
#define HID_CH  128
#define OUT_CH  64

#define NBLK ((N_NODES + 255) / 256)     // 391
#define FILL_RANGE ((N_NODES + 7) / 8)   // 12500
#define FILL_CHUNK 2048
#define FILL_NCHUNK ((N_EDGES + FILL_CHUNK - 1) / FILL_CHUNK)  // 782

// ---------------- CSR build ----------------

__global__ void k_zero(int* __restrict__ deg) {
    int i = blockIdx.x * 256 + threadIdx.x;
    if (i < N_NODES) deg[i] = 0;
}

// unchanged: atomic-throughput yardstick vs the new sharded fill
__global__ void k_count(const int* __restrict__ ei, int* __restrict__ deg) {
    int e = blockIdx.x * 256 + threadIdx.x;
    if (e < N_EDGES) atomicAdd(&deg[ei[N_EDGES + e]], 1);
}

// two-level scan: ks1 (per-block excl scan + block sums) -> ks2 (scan sums) -> ks3 (add base)
__global__ __launch_bounds__(256) void ks1(const int* __restrict__ deg,
                                           int* __restrict__ rowptr,
                                           int* __restrict__ bsum) {
    __shared__ int ws[4];
    const int t = threadIdx.x, lane = t & 63, wv = t >> 6;
    const int i = blockIdx.x * 256 + t;
    int v = (i < N_NODES) ? deg[i] : 0;
    int x = v;
    #pragma unroll
    for (int d = 1; d < 64; d <<= 1) {
        int y = __shfl_up(x, d, 64);
        if (lane >= d) x += y;
    }
    if (lane == 63) ws[wv] = x;
    __syncthreads();
    if (t == 0) {
        int c = 0;
        #pragma unroll
        for (int k = 0; k < 4; k++) { int tmp = ws[k]; ws[k] = c; c += tmp; }
        bsum[blockIdx.x] = c;
    }
    __syncthreads();
    if (i < N_NODES) rowptr[i] = ws[wv] + (x - v);  // block-local exclusive
}

__global__ __launch_bounds__(512) void ks2(int* __restrict__ bsum,
                                           int* __restrict__ rowptr) {
    __shared__ int ws[8];
    const int t = threadIdx.x, lane = t & 63, wv = t >> 6;
    int v = (t < NBLK) ? bsum[t] : 0;
    int x = v;
    #pragma unroll
    for (int d = 1; d < 64; d <<= 1) {
        int y = __shfl_up(x, d, 64);
        if (lane >= d) x += y;
    }
    if (lane == 63) ws[wv] = x;
    __syncthreads();
    if (wv == 0) {
        int s = (lane < 8) ? ws[lane] : 0;
        #pragma unroll
        for (int d = 1; d < 8; d <<= 1) {
            int y = __shfl_up(s, d, 64);
            if (lane >= d) s += y;
        }
        if (lane < 8) ws[lane] = s;
    }
    __syncthreads();
    int waveoff = (wv == 0) ? 0 : ws[wv - 1];
    if (t < NBLK) bsum[t] = waveoff + (x - v);  // exclusive base per block
    if (t == 0) rowptr[N_NODES] = ws[7];        // total edges
}

__global__ void ks3(const int* __restrict__ deg, int* __restrict__ rowptr,
                    int* __restrict__ cursor, float* __restrict__ dinv,
                    const int* __restrict__ bsum) {
    int i = blockIdx.x * 256 + threadIdx.x;
    if (i < N_NODES) {
        int v = rowptr[i] + bsum[blockIdx.x];
        rowptr[i] = v;
        cursor[i] = v;
        dinv[i]   = rsqrtf((float)(deg[i] + 1));  // +1 self-loop
    }
}

// dst-range-sharded fill: 8 blocks share one edge chunk; block handles range
// (blockIdx&7). With round-robin block->XCD placement each 800KB srcs slice is
// single-XCD-written -> lines collect all writes before one writeback.
// Correct under ANY block->XCD mapping (atomics give positions).
__global__ __launch_bounds__(256) void k_fill(const int* __restrict__ ei,
                                              int* __restrict__ cursor,
                                              int* __restrict__ srcs) {
    const int chunk = blockIdx.x >> 3;
    const int r     = blockIdx.x & 7;
    const int lo    = r * FILL_RANGE;
    const int hi    = lo + FILL_RANGE;
    const int base  = chunk * FILL_CHUNK;
    #pragma unroll
    for (int k = 0; k < FILL_CHUNK / 256; k++) {
        int e = base + k * 256 + threadIdx.x;   // coalesced per sub-iteration
        if (e < N_EDGES) {
            int d = ei[N_EDGES + e];
            if (d >= lo && d < hi) {
                int pos = atomicAdd(&cursor[d], 1);
                srcs[pos] = ei[e];
            }
        }
    }
}

// ---------------- GEMM (K=128 fixed) ----------------
template <int OC, int RPT>
__global__ __launch_bounds__(256) void k_gemm(const float* __restrict__ A,
                                              const float* __restrict__ W,
                                              float* __restrict__ out,
                                              int nrows) {
    constexpr int CG   = OC / 4;
    constexpr int RG   = 256 / CG;
    constexpr int ROWS = RG * RPT;   // 64
    constexpr int LDSP = 128 + 4;
    __shared__ float xs[ROWS][LDSP];

    const int tid  = threadIdx.x;
    const int row0 = blockIdx.x * ROWS;

    for (int idx = tid; idx < ROWS * 32; idx += 256) {
        int r = idx >> 5, c4 = idx & 31;
        int gr = row0 + r;
        if (gr >= nrows) gr = nrows - 1;
        float4 v = ((const float4*)(A + (size_t)gr * 128))[c4];
        float* dp = &xs[r][c4 * 4];
        dp[0] = v.x; dp[1] = v.y; dp[2] = v.z; dp[3] = v.w;
    }
    __syncthreads();

    const int cg = tid % CG;
    const int rg = tid / CG;

    float acc[RPT][4];
    #pragma unroll
    for (int r = 0; r < RPT; r++) acc[r][0] = acc[r][1] = acc[r][2] = acc[r][3] = 0.f;

    const float* Wp = W + cg * 4;
    for (int k = 0; k < 128; k += 4) {
        float4 w0 = *(const float4*)(Wp + (size_t)(k + 0) * OC);
        float4 w1 = *(const float4*)(Wp + (size_t)(k + 1) * OC);
        float4 w2 = *(const float4*)(Wp + (size_t)(k + 2) * OC);
        float4 w3 = *(const float4*)(Wp + (size_t)(k + 3) * OC);
        #pragma unroll
        for (int r = 0; r < RPT; r++) {
            float4 xv = *(const float4*)&xs[rg * RPT + r][k];
            acc[r][0] = fmaf(xv.w, w3.x, fmaf(xv.z, w2.x, fmaf(xv.y, w1.x, fmaf(xv.x, w0.x, acc[r][0]))));
            acc[r][1] = fmaf(xv.w, w3.y, fmaf(xv.z, w2.y, fmaf(xv.y, w1.y, fmaf(xv.x, w0.y, acc[r][1]))));
            acc[r][2] = fmaf(xv.w, w3.z, fmaf(xv.z, w2.z, fmaf(xv.y, w1.z, fmaf(xv.x, w0.z, acc[r][2]))));
            acc[r][3] = fmaf(xv.w, w3.w, fmaf(xv.z, w2.w, fmaf(xv.y, w1.w, fmaf(xv.x, w0.w, acc[r][3]))));
        }
    }

    #pragma unroll
    for (int r = 0; r < RPT; r++) {
        int gr = row0 + rg * RPT + r;
        if (gr < nrows) {
            float4 o = make_float4(acc[r][0], acc[r][1], acc[r][2], acc[r][3]);
            *(float4*)(out + (size_t)gr * OC + cg * 4) = o;
        }
    }
}

// ---------------- Aggregation: wave per node, no LDS/barriers ----------------
// 128ch: lane l owns float2 cols [2l,2l+1]. Edge indices/weights loaded 64 at a
// time coalesced, broadcast via __shfl.
__global__ __launch_bounds__(256) void k_agg128(const float* __restrict__ h,
                                                const int* __restrict__ rowptr,
                                                const int* __restrict__ srcs,
                                                const float* __restrict__ dinv,
                                                const float* __restrict__ bias,
                                                float* __restrict__ out,
                                                int relu) {
    const int wv = threadIdx.x >> 6, l = threadIdx.x & 63;
    const int i  = blockIdx.x * 4 + wv;   // grid*4 == N_NODES exactly
    const float di = dinv[i];
    const float2* __restrict__ h2 = (const float2*)h;

    float2 acc = h2[(size_t)i * 64 + l];
    const float sw = di * di;
    acc.x *= sw; acc.y *= sw;

    const int start = rowptr[i], end = rowptr[i + 1];
    for (int b = start; b < end; b += 64) {
        const int eb = min(end - b, 64);
        int s = 0; float w = 0.f;
        if (l < eb) { s = srcs[b + l]; w = dinv[s] * di; }
        for (int j = 0; j < eb; j++) {
            const int   sj = __shfl(s, j);
            const float wj = __shfl(w, j);
            const float2 hv = h2[(size_t)sj * 64 + l];
            acc.x = fmaf(hv.x, wj, acc.x);
            acc.y = fmaf(hv.y, wj, acc.y);
        }
    }
    const float2 bv = ((const float2*)bias)[l];
    acc.x += bv.x; acc.y += bv.y;
    if (relu) { acc.x = fmaxf(acc.x, 0.f); acc.y = fmaxf(acc.y, 0.f); }
    ((float2*)out)[(size_t)i * 64 + l] = acc;
}

__global__ __launch_bounds__(256) void k_agg64(const float* __restrict__ h,
                                               const int* __restrict__ rowptr,
                                               const int* __restrict__ srcs,
                                               const float* __restrict__ dinv,
                                               const float* __restrict__ bias,
                                               float* __restrict__ out,
                                               int relu) {
    const int wv = threadIdx.x >> 6, l = threadIdx.x & 63;
    const int i  = blockIdx.x * 4 + wv;
    const float di = dinv[i];

    float acc = h[(size_t)i * 64 + l] * (di * di);

    const int start = rowptr[i], end = rowptr[i + 1];
    for (int b = start; b < end; b += 64) {
        const int eb = min(end - b, 64);
        int s = 0; float w = 0.f;
        if (l < eb) { s = srcs[b + l]; w = dinv[s] * di; }
        for (int j = 0; j < eb; j++) {
            const int   sj = __shfl(s, j);
            const float wj = __shfl(w, j);
            acc = fmaf(h[(size_t)sj * 64 + l], wj, acc);
        }
    }
    acc += bias[l];
    if (relu) acc = fmaxf(acc, 0.f);
    out[(size_t)i * 64 + l] = acc;
}

// ---------------- launch ----------------

extern "C" void kernel_launch(void* const* d_in, const int* in_sizes, int n_in,
                              void* d_out, int out_size, void* d_ws, size_t ws_size,
                              hipStream_t stream) {
    const float* x  = (const float*)d_in[0];
    const int*   ei = (const int*)d_in[1];
    const float* W1 = (const float*)d_in[2];
    const float* b1 = (const float*)d_in[3];
    const float* W2 = (const float*)d_in[4];
    const float* b2 = (const float*)d_in[5];
    float* out = (float*)d_out;

    char* p = (char*)d_ws;
    size_t used = 0;
    auto alloc = [&](size_t bytes) {
        void* q = (void*)p;
        size_t pad = (bytes + 255) & ~(size_t)255;
        p += pad;
        used += pad;
        return q;
    };
    int*   deg    = (int*)alloc(sizeof(int) * N_NODES);
    int*   rowptr = (int*)alloc(sizeof(int) * (N_NODES + 1));
    int*   cursor = (int*)alloc(sizeof(int) * N_NODES);
    float* dinv   = (float*)alloc(sizeof(float) * N_NODES);
    int*   bsum   = (int*)alloc(sizeof(int) * NBLK);
    int*   srcs   = (int*)alloc(sizeof(int) * N_EDGES);
    float* h1     = (float*)alloc(sizeof(float) * (size_t)N_NODES * HID_CH);
    float* agg1   = (float*)alloc(sizeof(float) * (size_t)N_NODES * HID_CH);
    float* h2     = h1;  // h1 dead after agg1

    if (used > ws_size) return;

    k_zero<<<NBLK, 256, 0, stream>>>(deg);
    k_count<<<(N_EDGES + 255) / 256, 256, 0, stream>>>(ei, deg);
    ks1<<<NBLK, 256, 0, stream>>>(deg, rowptr, bsum);
    ks2<<<1, 512, 0, stream>>>(bsum, rowptr);
    ks3<<<NBLK, 256, 0, stream>>>(deg, rowptr, cursor, dinv, bsum);
    k_fill<<<FILL_NCHUNK * 8, 256, 0, stream>>>(ei, cursor, srcs);

    k_gemm<128, 8><<<(N_NODES + 63) / 64, 256, 0, stream>>>(x, W1, h1, N_NODES);
    k_agg128<<<N_NODES / 4, 256, 0, stream>>>(h1, rowptr, srcs, dinv, b1, agg1, 1);
    k_gemm<64, 4><<<(N_NODES + 63) / 64, 256, 0, stream>>>(agg1, W2, h2, N_NODES);
    k_agg64<<<N_NODES / 4, 256, 0, stream>>>(h2, rowptr, srcs, dinv, b2, out, 0);
}

// Round 3
// 434.924 us; speedup vs baseline: 1.3154x; 1.0978x over previous
//
#include <hip/hip_runtime.h>
#include <cstdint>
#include <cstddef>

#define N_NODES 100000
#define N_EDGES 1600000
#define IN_CH   128
#define HID_CH  128
#define OUT_CH  64

#define NBLK ((N_NODES + 255) / 256)     // 391
#define FILL_RANGE ((N_NODES + 7) / 8)   // 12500
#define FILL_CHUNK 2048
#define FILL_NCHUNK ((N_EDGES + FILL_CHUNK - 1) / FILL_CHUNK)  // 782
#define AGG_BLOCKS 2048

// ---------------- CSR build ----------------

__global__ void k_zero(int* __restrict__ deg) {
    int i = blockIdx.x * 256 + threadIdx.x;
    if (i < N_NODES) deg[i] = 0;
}

__global__ void k_count(const int* __restrict__ ei, int* __restrict__ deg) {
    int e = blockIdx.x * 256 + threadIdx.x;
    if (e < N_EDGES) atomicAdd(&deg[ei[N_EDGES + e]], 1);
}

__global__ __launch_bounds__(256) void ks1(const int* __restrict__ deg,
                                           int* __restrict__ rowptr,
                                           int* __restrict__ bsum) {
    __shared__ int ws[4];
    const int t = threadIdx.x, lane = t & 63, wv = t >> 6;
    const int i = blockIdx.x * 256 + t;
    int v = (i < N_NODES) ? deg[i] : 0;
    int x = v;
    #pragma unroll
    for (int d = 1; d < 64; d <<= 1) {
        int y = __shfl_up(x, d, 64);
        if (lane >= d) x += y;
    }
    if (lane == 63) ws[wv] = x;
    __syncthreads();
    if (t == 0) {
        int c = 0;
        #pragma unroll
        for (int k = 0; k < 4; k++) { int tmp = ws[k]; ws[k] = c; c += tmp; }
        bsum[blockIdx.x] = c;
    }
    __syncthreads();
    if (i < N_NODES) rowptr[i] = ws[wv] + (x - v);
}

__global__ __launch_bounds__(512) void ks2(int* __restrict__ bsum,
                                           int* __restrict__ rowptr) {
    __shared__ int ws[8];
    const int t = threadIdx.x, lane = t & 63, wv = t >> 6;
    int v = (t < NBLK) ? bsum[t] : 0;
    int x = v;
    #pragma unroll
    for (int d = 1; d < 64; d <<= 1) {
        int y = __shfl_up(x, d, 64);
        if (lane >= d) x += y;
    }
    if (lane == 63) ws[wv] = x;
    __syncthreads();
    if (wv == 0) {
        int s = (lane < 8) ? ws[lane] : 0;
        #pragma unroll
        for (int d = 1; d < 8; d <<= 1) {
            int y = __shfl_up(s, d, 64);
            if (lane >= d) s += y;
        }
        if (lane < 8) ws[lane] = s;
    }
    __syncthreads();
    int waveoff = (wv == 0) ? 0 : ws[wv - 1];
    if (t < NBLK) bsum[t] = waveoff + (x - v);
    if (t == 0) rowptr[N_NODES] = ws[7];
}

__global__ void ks3(const int* __restrict__ deg, int* __restrict__ rowptr,
                    int* __restrict__ cursor, float* __restrict__ dinv,
                    const int* __restrict__ bsum) {
    int i = blockIdx.x * 256 + threadIdx.x;
    if (i < N_NODES) {
        int v = rowptr[i] + bsum[blockIdx.x];
        rowptr[i] = v;
        cursor[i] = v;
        dinv[i]   = rsqrtf((float)(deg[i] + 1));
    }
}

__global__ __launch_bounds__(256) void k_fill(const int* __restrict__ ei,
                                              int* __restrict__ cursor,
                                              int* __restrict__ srcs) {
    const int chunk = blockIdx.x >> 3;
    const int r     = blockIdx.x & 7;
    const int lo    = r * FILL_RANGE;
    const int hi    = lo + FILL_RANGE;
    const int base  = chunk * FILL_CHUNK;
    #pragma unroll
    for (int k = 0; k < FILL_CHUNK / 256; k++) {
        int e = base + k * 256 + threadIdx.x;
        if (e < N_EDGES) {
            int d = ei[N_EDGES + e];
            if (d >= lo && d < hi) {
                int pos = atomicAdd(&cursor[d], 1);
                srcs[pos] = ei[e];
            }
        }
    }
}

// ---------------- GEMM (K=128 fixed) ----------------
template <int OC, int RPT>
__global__ __launch_bounds__(256) void k_gemm(const float* __restrict__ A,
                                              const float* __restrict__ W,
                                              float* __restrict__ out,
                                              int nrows) {
    constexpr int CG   = OC / 4;
    constexpr int RG   = 256 / CG;
    constexpr int ROWS = RG * RPT;   // 64
    constexpr int LDSP = 128 + 4;
    __shared__ float xs[ROWS][LDSP];

    const int tid  = threadIdx.x;
    const int row0 = blockIdx.x * ROWS;

    for (int idx = tid; idx < ROWS * 32; idx += 256) {
        int r = idx >> 5, c4 = idx & 31;
        int gr = row0 + r;
        if (gr >= nrows) gr = nrows - 1;
        float4 v = ((const float4*)(A + (size_t)gr * 128))[c4];
        float* dp = &xs[r][c4 * 4];
        dp[0] = v.x; dp[1] = v.y; dp[2] = v.z; dp[3] = v.w;
    }
    __syncthreads();

    const int cg = tid % CG;
    const int rg = tid / CG;

    float acc[RPT][4];
    #pragma unroll
    for (int r = 0; r < RPT; r++) acc[r][0] = acc[r][1] = acc[r][2] = acc[r][3] = 0.f;

    const float* Wp = W + cg * 4;
    for (int k = 0; k < 128; k += 4) {
        float4 w0 = *(const float4*)(Wp + (size_t)(k + 0) * OC);
        float4 w1 = *(const float4*)(Wp + (size_t)(k + 1) * OC);
        float4 w2 = *(const float4*)(Wp + (size_t)(k + 2) * OC);
        float4 w3 = *(const float4*)(Wp + (size_t)(k + 3) * OC);
        #pragma unroll
        for (int r = 0; r < RPT; r++) {
            float4 xv = *(const float4*)&xs[rg * RPT + r][k];
            acc[r][0] = fmaf(xv.w, w3.x, fmaf(xv.z, w2.x, fmaf(xv.y, w1.x, fmaf(xv.x, w0.x, acc[r][0]))));
            acc[r][1] = fmaf(xv.w, w3.y, fmaf(xv.z, w2.y, fmaf(xv.y, w1.y, fmaf(xv.x, w0.y, acc[r][1]))));
            acc[r][2] = fmaf(xv.w, w3.z, fmaf(xv.z, w2.z, fmaf(xv.y, w1.z, fmaf(xv.x, w0.z, acc[r][2]))));
            acc[r][3] = fmaf(xv.w, w3.w, fmaf(xv.z, w2.w, fmaf(xv.y, w1.w, fmaf(xv.x, w0.w, acc[r][3]))));
        }
    }

    #pragma unroll
    for (int r = 0; r < RPT; r++) {
        int gr = row0 + rg * RPT + r;
        if (gr < nrows) {
            float4 o = make_float4(acc[r][0], acc[r][1], acc[r][2], acc[r][3]);
            *(float4*)(out + (size_t)gr * OC + cg * 4) = o;
        }
    }
}

// ---------------- Aggregation: wave/node, 8-deep MLP unroll ----------------
// 128ch: lane l owns float2 cols [2l,2l+1]. Per 64-edge batch: coalesced
// srcs+weight load into lane regs, then 8 edges at a time: 16 independent
// shfl broadcasts, 8 independent row-gathers in flight, then 16 fmafs.
__global__ __launch_bounds__(256) void k_agg128(const float* __restrict__ h,
                                                const int* __restrict__ rowptr,
                                                const int* __restrict__ srcs,
                                                const float* __restrict__ dinv,
                                                const float* __restrict__ bias,
                                                float* __restrict__ out,
                                                int relu) {
    const int l = threadIdx.x & 63;
    const int wv0 = blockIdx.x * 4 + (threadIdx.x >> 6);
    const float2* __restrict__ h2 = (const float2*)h;
    const float2 bv = ((const float2*)bias)[l];

    for (int i = wv0; i < N_NODES; i += AGG_BLOCKS * 4) {
        const float di = dinv[i];
        float2 acc = h2[(size_t)i * 64 + l];
        const float sw = di * di;
        acc.x *= sw; acc.y *= sw;

        const int start = rowptr[i], end = rowptr[i + 1];
        for (int b = start; b < end; b += 64) {
            const int eb = min(end - b, 64);
            int s = 0; float w = 0.f;
            if (l < eb) { s = srcs[b + l]; w = dinv[s] * di; }
            int j = 0;
            for (; j + 8 <= eb; j += 8) {
                int   si[8]; float wi[8];
                #pragma unroll
                for (int u = 0; u < 8; u++) { si[u] = __shfl(s, j + u); wi[u] = __shfl(w, j + u); }
                float2 v[8];
                #pragma unroll
                for (int u = 0; u < 8; u++) v[u] = h2[(size_t)si[u] * 64 + l];
                #pragma unroll
                for (int u = 0; u < 8; u++) {
                    acc.x = fmaf(v[u].x, wi[u], acc.x);
                    acc.y = fmaf(v[u].y, wi[u], acc.y);
                }
            }
            for (; j < eb; j++) {
                const int   sj = __shfl(s, j);
                const float wj = __shfl(w, j);
                const float2 hv = h2[(size_t)sj * 64 + l];
                acc.x = fmaf(hv.x, wj, acc.x);
                acc.y = fmaf(hv.y, wj, acc.y);
            }
        }
        acc.x += bv.x; acc.y += bv.y;
        if (relu) { acc.x = fmaxf(acc.x, 0.f); acc.y = fmaxf(acc.y, 0.f); }
        ((float2*)out)[(size_t)i * 64 + l] = acc;
    }
}

__global__ __launch_bounds__(256) void k_agg64(const float* __restrict__ h,
                                               const int* __restrict__ rowptr,
                                               const int* __restrict__ srcs,
                                               const float* __restrict__ dinv,
                                               const float* __restrict__ bias,
                                               float* __restrict__ out,
                                               int relu) {
    const int l = threadIdx.x & 63;
    const int wv0 = blockIdx.x * 4 + (threadIdx.x >> 6);
    const float bi = bias[l];

    for (int i = wv0; i < N_NODES; i += AGG_BLOCKS * 4) {
        const float di = dinv[i];
        float acc = h[(size_t)i * 64 + l] * (di * di);

        const int start = rowptr[i], end = rowptr[i + 1];
        for (int b = start; b < end; b += 64) {
            const int eb = min(end - b, 64);
            int s = 0; float w = 0.f;
            if (l < eb) { s = srcs[b + l]; w = dinv[s] * di; }
            int j = 0;
            for (; j + 8 <= eb; j += 8) {
                int   si[8]; float wi[8];
                #pragma unroll
                for (int u = 0; u < 8; u++) { si[u] = __shfl(s, j + u); wi[u] = __shfl(w, j + u); }
                float v[8];
                #pragma unroll
                for (int u = 0; u < 8; u++) v[u] = h[(size_t)si[u] * 64 + l];
                #pragma unroll
                for (int u = 0; u < 8; u++) acc = fmaf(v[u], wi[u], acc);
            }
            for (; j < eb; j++) {
                const int   sj = __shfl(s, j);
                const float wj = __shfl(w, j);
                acc = fmaf(h[(size_t)sj * 64 + l], wj, acc);
            }
        }
        acc += bi;
        if (relu) acc = fmaxf(acc, 0.f);
        out[(size_t)i * 64 + l] = acc;
    }
}

// ---------------- launch ----------------

extern "C" void kernel_launch(void* const* d_in, const int* in_sizes, int n_in,
                              void* d_out, int out_size, void* d_ws, size_t ws_size,
                              hipStream_t stream) {
    const float* x  = (const float*)d_in[0];
    const int*   ei = (const int*)d_in[1];
    const float* W1 = (const float*)d_in[2];
    const float* b1 = (const float*)d_in[3];
    const float* W2 = (const float*)d_in[4];
    const float* b2 = (const float*)d_in[5];
    float* out = (float*)d_out;

    char* p = (char*)d_ws;
    size_t used = 0;
    auto alloc = [&](size_t bytes) {
        void* q = (void*)p;
        size_t pad = (bytes + 255) & ~(size_t)255;
        p += pad;
        used += pad;
        return q;
    };
    int*   deg    = (int*)alloc(sizeof(int) * N_NODES);
    int*   rowptr = (int*)alloc(sizeof(int) * (N_NODES + 1));
    int*   cursor = (int*)alloc(sizeof(int) * N_NODES);
    float* dinv   = (float*)alloc(sizeof(float) * N_NODES);
    int*   bsum   = (int*)alloc(sizeof(int) * NBLK);
    int*   srcs   = (int*)alloc(sizeof(int) * N_EDGES);
    float* h1     = (float*)alloc(sizeof(float) * (size_t)N_NODES * HID_CH);
    float* agg1   = (float*)alloc(sizeof(float) * (size_t)N_NODES * HID_CH);
    float* h2     = h1;  // h1 dead after agg1

    if (used > ws_size) return;

    k_zero<<<NBLK, 256, 0, stream>>>(deg);
    k_count<<<(N_EDGES + 255) / 256, 256, 0, stream>>>(ei, deg);
    ks1<<<NBLK, 256, 0, stream>>>(deg, rowptr, bsum);
    ks2<<<1, 512, 0, stream>>>(bsum, rowptr);
    ks3<<<NBLK, 256, 0, stream>>>(deg, rowptr, cursor, dinv, bsum);
    k_fill<<<FILL_NCHUNK * 8, 256, 0, stream>>>(ei, cursor, srcs);

    k_gemm<128, 8><<<(N_NODES + 63) / 64, 256, 0, stream>>>(x, W1, h1, N_NODES);
    k_agg128<<<AGG_BLOCKS, 256, 0, stream>>>(h1, rowptr, srcs, dinv, b1, agg1, 1);
    k_gemm<64, 4><<<(N_NODES + 63) / 64, 256, 0, stream>>>(agg1, W2, h2, N_NODES);
    k_agg64<<<AGG_BLOCKS, 256, 0, stream>>>(h2, rowptr, srcs, dinv, b2, out, 0);
}

// Round 4
// 378.828 us; speedup vs baseline: 1.5102x; 1.1481x over previous
//
#include <hip/hip_runtime.h>
#include <cstdint>
#include <cstddef>

#define N_NODES 100000
#define N_EDGES 1600000
#define IN_CH   128
#define HID_CH  128
#define OUT_CH  64

#define NBLK ((N_NODES + 255) / 256)     // 391
#define FILL_RANGE ((N_NODES + 7) / 8)   // 12500
#define FILL_CHUNK 2048
#define FILL_NCHUNK ((N_EDGES + FILL_CHUNK - 1) / FILL_CHUNK)  // 782
#define AGG_BLOCKS 2048

__device__ __forceinline__ unsigned short f2bf(float f) {
    unsigned int u = __float_as_uint(f);
    unsigned int r = (u + 0x7FFFu + ((u >> 16) & 1u)) >> 16;   // RNE
    return (unsigned short)r;
}
__device__ __forceinline__ float bfbits2f(unsigned int lo16) {
    return __uint_as_float(lo16 << 16);
}

// ---------------- CSR build ----------------

__global__ void k_zero(int* __restrict__ deg) {
    int i = blockIdx.x * 256 + threadIdx.x;
    if (i < N_NODES) deg[i] = 0;
}

// dst-range-sharded count (same pattern as k_fill: atomics stay in one XCD's L2)
__global__ __launch_bounds__(256) void k_count(const int* __restrict__ ei,
                                               int* __restrict__ deg) {
    const int chunk = blockIdx.x >> 3;
    const int r     = blockIdx.x & 7;
    const int lo    = r * FILL_RANGE;
    const int hi    = lo + FILL_RANGE;
    const int base  = chunk * FILL_CHUNK;
    #pragma unroll
    for (int k = 0; k < FILL_CHUNK / 256; k++) {
        int e = base + k * 256 + threadIdx.x;
        if (e < N_EDGES) {
            int d = ei[N_EDGES + e];
            if (d >= lo && d < hi) atomicAdd(&deg[d], 1);
        }
    }
}

__global__ __launch_bounds__(256) void ks1(const int* __restrict__ deg,
                                           int* __restrict__ rowptr,
                                           int* __restrict__ bsum) {
    __shared__ int ws[4];
    const int t = threadIdx.x, lane = t & 63, wv = t >> 6;
    const int i = blockIdx.x * 256 + t;
    int v = (i < N_NODES) ? deg[i] : 0;
    int x = v;
    #pragma unroll
    for (int d = 1; d < 64; d <<= 1) {
        int y = __shfl_up(x, d, 64);
        if (lane >= d) x += y;
    }
    if (lane == 63) ws[wv] = x;
    __syncthreads();
    if (t == 0) {
        int c = 0;
        #pragma unroll
        for (int k = 0; k < 4; k++) { int tmp = ws[k]; ws[k] = c; c += tmp; }
        bsum[blockIdx.x] = c;
    }
    __syncthreads();
    if (i < N_NODES) rowptr[i] = ws[wv] + (x - v);
}

__global__ __launch_bounds__(512) void ks2(int* __restrict__ bsum,
                                           int* __restrict__ rowptr) {
    __shared__ int ws[8];
    const int t = threadIdx.x, lane = t & 63, wv = t >> 6;
    int v = (t < NBLK) ? bsum[t] : 0;
    int x = v;
    #pragma unroll
    for (int d = 1; d < 64; d <<= 1) {
        int y = __shfl_up(x, d, 64);
        if (lane >= d) x += y;
    }
    if (lane == 63) ws[wv] = x;
    __syncthreads();
    if (wv == 0) {
        int s = (lane < 8) ? ws[lane] : 0;
        #pragma unroll
        for (int d = 1; d < 8; d <<= 1) {
            int y = __shfl_up(s, d, 64);
            if (lane >= d) s += y;
        }
        if (lane < 8) ws[lane] = s;
    }
    __syncthreads();
    int waveoff = (wv == 0) ? 0 : ws[wv - 1];
    if (t < NBLK) bsum[t] = waveoff + (x - v);
    if (t == 0) rowptr[N_NODES] = ws[7];
}

__global__ void ks3(const int* __restrict__ deg, int* __restrict__ rowptr,
                    int* __restrict__ cursor, float* __restrict__ dinv,
                    const int* __restrict__ bsum) {
    int i = blockIdx.x * 256 + threadIdx.x;
    if (i < N_NODES) {
        int v = rowptr[i] + bsum[blockIdx.x];
        rowptr[i] = v;
        cursor[i] = v;
        dinv[i]   = rsqrtf((float)(deg[i] + 1));
    }
}

__global__ __launch_bounds__(256) void k_fill(const int* __restrict__ ei,
                                              int* __restrict__ cursor,
                                              int* __restrict__ srcs) {
    const int chunk = blockIdx.x >> 3;
    const int r     = blockIdx.x & 7;
    const int lo    = r * FILL_RANGE;
    const int hi    = lo + FILL_RANGE;
    const int base  = chunk * FILL_CHUNK;
    #pragma unroll
    for (int k = 0; k < FILL_CHUNK / 256; k++) {
        int e = base + k * 256 + threadIdx.x;
        if (e < N_EDGES) {
            int d = ei[N_EDGES + e];
            if (d >= lo && d < hi) {
                int pos = atomicAdd(&cursor[d], 1);
                srcs[pos] = ei[e];
            }
        }
    }
}

// ---------------- GEMM (K=128 fixed), fp32 compute ----------------
// OUT_BF16: pack output rows to bf16 (gather table for the aggregation).
template <int OC, int RPT, int OUT_BF16>
__global__ __launch_bounds__(256) void k_gemm(const float* __restrict__ A,
                                              const float* __restrict__ W,
                                              void* __restrict__ outp,
                                              int nrows) {
    constexpr int CG   = OC / 4;
    constexpr int RG   = 256 / CG;
    constexpr int ROWS = RG * RPT;   // 64
    constexpr int LDSP = 128 + 4;
    __shared__ float xs[ROWS][LDSP];

    const int tid  = threadIdx.x;
    const int row0 = blockIdx.x * ROWS;

    for (int idx = tid; idx < ROWS * 32; idx += 256) {
        int r = idx >> 5, c4 = idx & 31;
        int gr = row0 + r;
        if (gr >= nrows) gr = nrows - 1;
        float4 v = ((const float4*)(A + (size_t)gr * 128))[c4];
        float* dp = &xs[r][c4 * 4];
        dp[0] = v.x; dp[1] = v.y; dp[2] = v.z; dp[3] = v.w;
    }
    __syncthreads();

    const int cg = tid % CG;
    const int rg = tid / CG;

    float acc[RPT][4];
    #pragma unroll
    for (int r = 0; r < RPT; r++) acc[r][0] = acc[r][1] = acc[r][2] = acc[r][3] = 0.f;

    const float* Wp = W + cg * 4;
    for (int k = 0; k < 128; k += 4) {
        float4 w0 = *(const float4*)(Wp + (size_t)(k + 0) * OC);
        float4 w1 = *(const float4*)(Wp + (size_t)(k + 1) * OC);
        float4 w2 = *(const float4*)(Wp + (size_t)(k + 2) * OC);
        float4 w3 = *(const float4*)(Wp + (size_t)(k + 3) * OC);
        #pragma unroll
        for (int r = 0; r < RPT; r++) {
            float4 xv = *(const float4*)&xs[rg * RPT + r][k];
            acc[r][0] = fmaf(xv.w, w3.x, fmaf(xv.z, w2.x, fmaf(xv.y, w1.x, fmaf(xv.x, w0.x, acc[r][0]))));
            acc[r][1] = fmaf(xv.w, w3.y, fmaf(xv.z, w2.y, fmaf(xv.y, w1.y, fmaf(xv.x, w0.y, acc[r][1]))));
            acc[r][2] = fmaf(xv.w, w3.z, fmaf(xv.z, w2.z, fmaf(xv.y, w1.z, fmaf(xv.x, w0.z, acc[r][2]))));
            acc[r][3] = fmaf(xv.w, w3.w, fmaf(xv.z, w2.w, fmaf(xv.y, w1.w, fmaf(xv.x, w0.w, acc[r][3]))));
        }
    }

    #pragma unroll
    for (int r = 0; r < RPT; r++) {
        int gr = row0 + rg * RPT + r;
        if (gr < nrows) {
            if (OUT_BF16) {
                unsigned int p0 = (unsigned int)f2bf(acc[r][0]) | ((unsigned int)f2bf(acc[r][1]) << 16);
                unsigned int p1 = (unsigned int)f2bf(acc[r][2]) | ((unsigned int)f2bf(acc[r][3]) << 16);
                uint2* o = (uint2*)outp;
                o[(size_t)gr * (OC / 4) + cg] = make_uint2(p0, p1);
            } else {
                float4 o = make_float4(acc[r][0], acc[r][1], acc[r][2], acc[r][3]);
                *(float4*)((float*)outp + (size_t)gr * OC + cg * 4) = o;
            }
        }
    }
}

// ---------------- Aggregation ----------------
// 128ch over a bf16 table: lane l owns channels 2l,2l+1 packed in one uint.
__global__ __launch_bounds__(256) void k_agg128bf(const unsigned int* __restrict__ hb,
                                                  const int* __restrict__ rowptr,
                                                  const int* __restrict__ srcs,
                                                  const float* __restrict__ dinv,
                                                  const float* __restrict__ bias,
                                                  float* __restrict__ out,
                                                  int relu) {
    const int l = threadIdx.x & 63;
    const int wv0 = blockIdx.x * 4 + (threadIdx.x >> 6);
    const float2 bv = ((const float2*)bias)[l];

    for (int i = wv0; i < N_NODES; i += AGG_BLOCKS * 4) {
        const float di = dinv[i];
        unsigned int sv = hb[(size_t)i * 64 + l];
        const float sw = di * di;
        float2 acc;
        acc.x = bfbits2f(sv & 0xFFFFu) * sw;
        acc.y = bfbits2f(sv >> 16) * sw;

        const int start = rowptr[i], end = rowptr[i + 1];
        for (int b = start; b < end; b += 64) {
            const int eb = min(end - b, 64);
            int s = 0; float w = 0.f;
            if (l < eb) { s = srcs[b + l]; w = dinv[s] * di; }
            int j = 0;
            for (; j + 8 <= eb; j += 8) {
                int   si[8]; float wi[8];
                #pragma unroll
                for (int u = 0; u < 8; u++) { si[u] = __shfl(s, j + u); wi[u] = __shfl(w, j + u); }
                unsigned int v[8];
                #pragma unroll
                for (int u = 0; u < 8; u++) v[u] = hb[(size_t)si[u] * 64 + l];
                #pragma unroll
                for (int u = 0; u < 8; u++) {
                    acc.x = fmaf(bfbits2f(v[u] & 0xFFFFu), wi[u], acc.x);
                    acc.y = fmaf(bfbits2f(v[u] >> 16),     wi[u], acc.y);
                }
            }
            for (; j < eb; j++) {
                const int   sj = __shfl(s, j);
                const float wj = __shfl(w, j);
                unsigned int v = hb[(size_t)sj * 64 + l];
                acc.x = fmaf(bfbits2f(v & 0xFFFFu), wj, acc.x);
                acc.y = fmaf(bfbits2f(v >> 16),     wj, acc.y);
            }
        }
        acc.x += bv.x; acc.y += bv.y;
        if (relu) { acc.x = fmaxf(acc.x, 0.f); acc.y = fmaxf(acc.y, 0.f); }
        ((float2*)out)[(size_t)i * 64 + l] = acc;
    }
}

// 64ch fp32 gather (precision hedge: errors here hit the output directly)
__global__ __launch_bounds__(256) void k_agg64(const float* __restrict__ h,
                                               const int* __restrict__ rowptr,
                                               const int* __restrict__ srcs,
                                               const float* __restrict__ dinv,
                                               const float* __restrict__ bias,
                                               float* __restrict__ out,
                                               int relu) {
    const int l = threadIdx.x & 63;
    const int wv0 = blockIdx.x * 4 + (threadIdx.x >> 6);
    const float bi = bias[l];

    for (int i = wv0; i < N_NODES; i += AGG_BLOCKS * 4) {
        const float di = dinv[i];
        float acc = h[(size_t)i * 64 + l] * (di * di);

        const int start = rowptr[i], end = rowptr[i + 1];
        for (int b = start; b < end; b += 64) {
            const int eb = min(end - b, 64);
            int s = 0; float w = 0.f;
            if (l < eb) { s = srcs[b + l]; w = dinv[s] * di; }
            int j = 0;
            for (; j + 8 <= eb; j += 8) {
                int   si[8]; float wi[8];
                #pragma unroll
                for (int u = 0; u < 8; u++) { si[u] = __shfl(s, j + u); wi[u] = __shfl(w, j + u); }
                float v[8];
                #pragma unroll
                for (int u = 0; u < 8; u++) v[u] = h[(size_t)si[u] * 64 + l];
                #pragma unroll
                for (int u = 0; u < 8; u++) acc = fmaf(v[u], wi[u], acc);
            }
            for (; j < eb; j++) {
                const int   sj = __shfl(s, j);
                const float wj = __shfl(w, j);
                acc = fmaf(h[(size_t)sj * 64 + l], wj, acc);
            }
        }
        acc += bi;
        if (relu) acc = fmaxf(acc, 0.f);
        out[(size_t)i * 64 + l] = acc;
    }
}

// ---------------- launch ----------------

extern "C" void kernel_launch(void* const* d_in, const int* in_sizes, int n_in,
                              void* d_out, int out_size, void* d_ws, size_t ws_size,
                              hipStream_t stream) {
    const float* x  = (const float*)d_in[0];
    const int*   ei = (const int*)d_in[1];
    const float* W1 = (const float*)d_in[2];
    const float* b1 = (const float*)d_in[3];
    const float* W2 = (const float*)d_in[4];
    const float* b2 = (const float*)d_in[5];
    float* out = (float*)d_out;

    char* p = (char*)d_ws;
    size_t used = 0;
    auto alloc = [&](size_t bytes) {
        void* q = (void*)p;
        size_t pad = (bytes + 255) & ~(size_t)255;
        p += pad;
        used += pad;
        return q;
    };
    int*   deg    = (int*)alloc(sizeof(int) * N_NODES);
    int*   rowptr = (int*)alloc(sizeof(int) * (N_NODES + 1));
    int*   cursor = (int*)alloc(sizeof(int) * N_NODES);
    float* dinv   = (float*)alloc(sizeof(float) * N_NODES);
    int*   bsum   = (int*)alloc(sizeof(int) * NBLK);
    int*   srcs   = (int*)alloc(sizeof(int) * N_EDGES);
    unsigned int* h1b = (unsigned int*)alloc(sizeof(unsigned int) * (size_t)N_NODES * 64); // bf16 x 128ch
    float* agg1   = (float*)alloc(sizeof(float) * (size_t)N_NODES * HID_CH);
    float* h2     = (float*)h1b;  // h1b dead after agg128; h2 is 64ch fp32, same 25.6MB

    if (used > ws_size) return;

    k_zero<<<NBLK, 256, 0, stream>>>(deg);
    k_count<<<FILL_NCHUNK * 8, 256, 0, stream>>>(ei, deg);
    ks1<<<NBLK, 256, 0, stream>>>(deg, rowptr, bsum);
    ks2<<<1, 512, 0, stream>>>(bsum, rowptr);
    ks3<<<NBLK, 256, 0, stream>>>(deg, rowptr, cursor, dinv, bsum);
    k_fill<<<FILL_NCHUNK * 8, 256, 0, stream>>>(ei, cursor, srcs);

    k_gemm<128, 8, 1><<<(N_NODES + 63) / 64, 256, 0, stream>>>(x, W1, (void*)h1b, N_NODES);
    k_agg128bf<<<AGG_BLOCKS, 256, 0, stream>>>(h1b, rowptr, srcs, dinv, b1, agg1, 1);
    k_gemm<64, 4, 0><<<(N_NODES + 63) / 64, 256, 0, stream>>>(agg1, W2, (void*)h2, N_NODES);
    k_agg64<<<AGG_BLOCKS, 256, 0, stream>>>(h2, rowptr, srcs, dinv, b2, out, 0);
}

// Round 5
// 368.627 us; speedup vs baseline: 1.5520x; 1.0277x over previous
//
#include <hip/hip_runtime.h>
#include <cstdint>
#include <cstddef>

#define N_NODES 100000
#define N_EDGES 1600000
#define IN_CH   128
#define HID_CH  128
#define OUT_CH  64

#define NBLK ((N_NODES + 255) / 256)     // 391
#define FILL_RANGE ((N_NODES + 7) / 8)   // 12500
#define FILL_CHUNK 2048
#define FILL_NCHUNK ((N_EDGES + FILL_CHUNK - 1) / FILL_CHUNK)  // 782
#define AGG_BLOCKS 2048

__device__ __forceinline__ unsigned short f2bf(float f) {
    unsigned int u = __float_as_uint(f);
    unsigned int r = (u + 0x7FFFu + ((u >> 16) & 1u)) >> 16;   // RNE
    return (unsigned short)r;
}
__device__ __forceinline__ float bfbits2f(unsigned int lo16) {
    return __uint_as_float(lo16 << 16);
}

// ---------------- CSR build ----------------
// dst-range-sharded count; NT loads keep streaming ei out of L2 so the
// (small, hot) deg/cursor/srcs lines stay resident.
__global__ __launch_bounds__(256) void k_count(const int* __restrict__ ei,
                                               int* __restrict__ deg) {
    const int chunk = blockIdx.x >> 3;
    const int r     = blockIdx.x & 7;
    const int lo    = r * FILL_RANGE;
    const int hi    = lo + FILL_RANGE;
    const int base  = chunk * FILL_CHUNK;
    #pragma unroll
    for (int k = 0; k < FILL_CHUNK / 256; k++) {
        int e = base + k * 256 + threadIdx.x;
        if (e < N_EDGES) {
            int d = __builtin_nontemporal_load(ei + N_EDGES + e);
            if (d >= lo && d < hi) atomicAdd(&deg[d], 1);
        }
    }
}

__global__ __launch_bounds__(256) void ks1(const int* __restrict__ deg,
                                           int* __restrict__ rowptr,
                                           int* __restrict__ bsum) {
    __shared__ int ws[4];
    const int t = threadIdx.x, lane = t & 63, wv = t >> 6;
    const int i = blockIdx.x * 256 + t;
    int v = (i < N_NODES) ? deg[i] : 0;
    int x = v;
    #pragma unroll
    for (int d = 1; d < 64; d <<= 1) {
        int y = __shfl_up(x, d, 64);
        if (lane >= d) x += y;
    }
    if (lane == 63) ws[wv] = x;
    __syncthreads();
    if (t == 0) {
        int c = 0;
        #pragma unroll
        for (int k = 0; k < 4; k++) { int tmp = ws[k]; ws[k] = c; c += tmp; }
        bsum[blockIdx.x] = c;
    }
    __syncthreads();
    if (i < N_NODES) rowptr[i] = ws[wv] + (x - v);
}

__global__ __launch_bounds__(512) void ks2(int* __restrict__ bsum,
                                           int* __restrict__ rowptr) {
    __shared__ int ws[8];
    const int t = threadIdx.x, lane = t & 63, wv = t >> 6;
    int v = (t < NBLK) ? bsum[t] : 0;
    int x = v;
    #pragma unroll
    for (int d = 1; d < 64; d <<= 1) {
        int y = __shfl_up(x, d, 64);
        if (lane >= d) x += y;
    }
    if (lane == 63) ws[wv] = x;
    __syncthreads();
    if (wv == 0) {
        int s = (lane < 8) ? ws[lane] : 0;
        #pragma unroll
        for (int d = 1; d < 8; d <<= 1) {
            int y = __shfl_up(s, d, 64);
            if (lane >= d) s += y;
        }
        if (lane < 8) ws[lane] = s;
    }
    __syncthreads();
    int waveoff = (wv == 0) ? 0 : ws[wv - 1];
    if (t < NBLK) bsum[t] = waveoff + (x - v);
    if (t == 0) rowptr[N_NODES] = ws[7];
}

__global__ void ks3(const int* __restrict__ deg, int* __restrict__ rowptr,
                    int* __restrict__ cursor, float* __restrict__ dinv,
                    const int* __restrict__ bsum) {
    int i = blockIdx.x * 256 + threadIdx.x;
    if (i < N_NODES) {
        int v = rowptr[i] + bsum[blockIdx.x];
        rowptr[i] = v;
        cursor[i] = v;
        dinv[i]   = rsqrtf((float)(deg[i] + 1));
    }
}

__global__ __launch_bounds__(256) void k_fill(const int* __restrict__ ei,
                                              int* __restrict__ cursor,
                                              int* __restrict__ srcs) {
    const int chunk = blockIdx.x >> 3;
    const int r     = blockIdx.x & 7;
    const int lo    = r * FILL_RANGE;
    const int hi    = lo + FILL_RANGE;
    const int base  = chunk * FILL_CHUNK;
    #pragma unroll
    for (int k = 0; k < FILL_CHUNK / 256; k++) {
        int e = base + k * 256 + threadIdx.x;
        if (e < N_EDGES) {
            int d = __builtin_nontemporal_load(ei + N_EDGES + e);
            if (d >= lo && d < hi) {
                int s = __builtin_nontemporal_load(ei + e);
                int pos = atomicAdd(&cursor[d], 1);
                srcs[pos] = s;
            }
        }
    }
}

// ---------------- GEMM (K=128 fixed), fp32 compute ----------------
// OUT_BF16: pack output rows to bf16 (gather table for the aggregation).
template <int OC, int RPT, int OUT_BF16>
__global__ __launch_bounds__(256) void k_gemm(const float* __restrict__ A,
                                              const float* __restrict__ W,
                                              void* __restrict__ outp,
                                              int nrows) {
    constexpr int CG   = OC / 4;
    constexpr int RG   = 256 / CG;
    constexpr int ROWS = RG * RPT;   // 64
    constexpr int LDSP = 128 + 4;
    __shared__ float xs[ROWS][LDSP];

    const int tid  = threadIdx.x;
    const int row0 = blockIdx.x * ROWS;

    for (int idx = tid; idx < ROWS * 32; idx += 256) {
        int r = idx >> 5, c4 = idx & 31;
        int gr = row0 + r;
        if (gr >= nrows) gr = nrows - 1;
        float4 v = ((const float4*)(A + (size_t)gr * 128))[c4];
        float* dp = &xs[r][c4 * 4];
        dp[0] = v.x; dp[1] = v.y; dp[2] = v.z; dp[3] = v.w;
    }
    __syncthreads();

    const int cg = tid % CG;
    const int rg = tid / CG;

    float acc[RPT][4];
    #pragma unroll
    for (int r = 0; r < RPT; r++) acc[r][0] = acc[r][1] = acc[r][2] = acc[r][3] = 0.f;

    const float* Wp = W + cg * 4;
    for (int k = 0; k < 128; k += 4) {
        float4 w0 = *(const float4*)(Wp + (size_t)(k + 0) * OC);
        float4 w1 = *(const float4*)(Wp + (size_t)(k + 1) * OC);
        float4 w2 = *(const float4*)(Wp + (size_t)(k + 2) * OC);
        float4 w3 = *(const float4*)(Wp + (size_t)(k + 3) * OC);
        #pragma unroll
        for (int r = 0; r < RPT; r++) {
            float4 xv = *(const float4*)&xs[rg * RPT + r][k];
            acc[r][0] = fmaf(xv.w, w3.x, fmaf(xv.z, w2.x, fmaf(xv.y, w1.x, fmaf(xv.x, w0.x, acc[r][0]))));
            acc[r][1] = fmaf(xv.w, w3.y, fmaf(xv.z, w2.y, fmaf(xv.y, w1.y, fmaf(xv.x, w0.y, acc[r][1]))));
            acc[r][2] = fmaf(xv.w, w3.z, fmaf(xv.z, w2.z, fmaf(xv.y, w1.z, fmaf(xv.x, w0.z, acc[r][2]))));
            acc[r][3] = fmaf(xv.w, w3.w, fmaf(xv.z, w2.w, fmaf(xv.y, w1.w, fmaf(xv.x, w0.w, acc[r][3]))));
        }
    }

    #pragma unroll
    for (int r = 0; r < RPT; r++) {
        int gr = row0 + rg * RPT + r;
        if (gr < nrows) {
            if (OUT_BF16) {
                unsigned int p0 = (unsigned int)f2bf(acc[r][0]) | ((unsigned int)f2bf(acc[r][1]) << 16);
                unsigned int p1 = (unsigned int)f2bf(acc[r][2]) | ((unsigned int)f2bf(acc[r][3]) << 16);
                uint2* o = (uint2*)outp;
                o[(size_t)gr * (OC / 4) + cg] = make_uint2(p0, p1);
            } else {
                float4 o = make_float4(acc[r][0], acc[r][1], acc[r][2], acc[r][3]);
                *(float4*)((float*)outp + (size_t)gr * OC + cg * 4) = o;
            }
        }
    }
}

// ---------------- Aggregation ----------------
// 128ch over bf16 table: lane l owns channels 2l,2l+1 packed in one uint.
__global__ __launch_bounds__(256) void k_agg128bf(const unsigned int* __restrict__ hb,
                                                  const int* __restrict__ rowptr,
                                                  const int* __restrict__ srcs,
                                                  const float* __restrict__ dinv,
                                                  const float* __restrict__ bias,
                                                  float* __restrict__ out,
                                                  int relu) {
    const int l = threadIdx.x & 63;
    const int wv0 = blockIdx.x * 4 + (threadIdx.x >> 6);
    const float2 bv = ((const float2*)bias)[l];

    for (int i = wv0; i < N_NODES; i += AGG_BLOCKS * 4) {
        const float di = dinv[i];
        unsigned int sv = hb[(size_t)i * 64 + l];
        const float sw = di * di;
        float2 acc;
        acc.x = bfbits2f(sv & 0xFFFFu) * sw;
        acc.y = bfbits2f(sv >> 16) * sw;

        const int start = rowptr[i], end = rowptr[i + 1];
        for (int b = start; b < end; b += 64) {
            const int eb = min(end - b, 64);
            int s = 0; float w = 0.f;
            if (l < eb) { s = srcs[b + l]; w = dinv[s] * di; }
            int j = 0;
            for (; j + 8 <= eb; j += 8) {
                int   si[8]; float wi[8];
                #pragma unroll
                for (int u = 0; u < 8; u++) { si[u] = __shfl(s, j + u); wi[u] = __shfl(w, j + u); }
                unsigned int v[8];
                #pragma unroll
                for (int u = 0; u < 8; u++) v[u] = hb[(size_t)si[u] * 64 + l];
                #pragma unroll
                for (int u = 0; u < 8; u++) {
                    acc.x = fmaf(bfbits2f(v[u] & 0xFFFFu), wi[u], acc.x);
                    acc.y = fmaf(bfbits2f(v[u] >> 16),     wi[u], acc.y);
                }
            }
            for (; j < eb; j++) {
                const int   sj = __shfl(s, j);
                const float wj = __shfl(w, j);
                unsigned int v = hb[(size_t)sj * 64 + l];
                acc.x = fmaf(bfbits2f(v & 0xFFFFu), wj, acc.x);
                acc.y = fmaf(bfbits2f(v >> 16),     wj, acc.y);
            }
        }
        acc.x += bv.x; acc.y += bv.y;
        if (relu) { acc.x = fmaxf(acc.x, 0.f); acc.y = fmaxf(acc.y, 0.f); }
        ((float2*)out)[(size_t)i * 64 + l] = acc;
    }
}

// 64ch over bf16 table: lane l owns channel l (ushort load, 128B/row coalesced).
__global__ __launch_bounds__(256) void k_agg64bf(const unsigned short* __restrict__ hb,
                                                 const int* __restrict__ rowptr,
                                                 const int* __restrict__ srcs,
                                                 const float* __restrict__ dinv,
                                                 const float* __restrict__ bias,
                                                 float* __restrict__ out,
                                                 int relu) {
    const int l = threadIdx.x & 63;
    const int wv0 = blockIdx.x * 4 + (threadIdx.x >> 6);
    const float bi = bias[l];

    for (int i = wv0; i < N_NODES; i += AGG_BLOCKS * 4) {
        const float di = dinv[i];
        float acc = bfbits2f((unsigned int)hb[(size_t)i * 64 + l]) * (di * di);

        const int start = rowptr[i], end = rowptr[i + 1];
        for (int b = start; b < end; b += 64) {
            const int eb = min(end - b, 64);
            int s = 0; float w = 0.f;
            if (l < eb) { s = srcs[b + l]; w = dinv[s] * di; }
            int j = 0;
            for (; j + 8 <= eb; j += 8) {
                int   si[8]; float wi[8];
                #pragma unroll
                for (int u = 0; u < 8; u++) { si[u] = __shfl(s, j + u); wi[u] = __shfl(w, j + u); }
                unsigned short v[8];
                #pragma unroll
                for (int u = 0; u < 8; u++) v[u] = hb[(size_t)si[u] * 64 + l];
                #pragma unroll
                for (int u = 0; u < 8; u++) acc = fmaf(bfbits2f((unsigned int)v[u]), wi[u], acc);
            }
            for (; j < eb; j++) {
                const int   sj = __shfl(s, j);
                const float wj = __shfl(w, j);
                acc = fmaf(bfbits2f((unsigned int)hb[(size_t)sj * 64 + l]), wj, acc);
            }
        }
        acc += bi;
        if (relu) acc = fmaxf(acc, 0.f);
        out[(size_t)i * 64 + l] = acc;
    }
}

// ---------------- launch ----------------

extern "C" void kernel_launch(void* const* d_in, const int* in_sizes, int n_in,
                              void* d_out, int out_size, void* d_ws, size_t ws_size,
                              hipStream_t stream) {
    const float* x  = (const float*)d_in[0];
    const int*   ei = (const int*)d_in[1];
    const float* W1 = (const float*)d_in[2];
    const float* b1 = (const float*)d_in[3];
    const float* W2 = (const float*)d_in[4];
    const float* b2 = (const float*)d_in[5];
    float* out = (float*)d_out;

    char* p = (char*)d_ws;
    size_t used = 0;
    auto alloc = [&](size_t bytes) {
        void* q = (void*)p;
        size_t pad = (bytes + 255) & ~(size_t)255;
        p += pad;
        used += pad;
        return q;
    };
    int*   deg    = (int*)alloc(sizeof(int) * N_NODES);
    int*   rowptr = (int*)alloc(sizeof(int) * (N_NODES + 1));
    int*   cursor = (int*)alloc(sizeof(int) * N_NODES);
    float* dinv   = (float*)alloc(sizeof(float) * N_NODES);
    int*   bsum   = (int*)alloc(sizeof(int) * NBLK);
    int*   srcs   = (int*)alloc(sizeof(int) * N_EDGES);
    unsigned int* h1b = (unsigned int*)alloc(sizeof(unsigned int) * (size_t)N_NODES * 64); // bf16 x 128ch
    float* agg1   = (float*)alloc(sizeof(float) * (size_t)N_NODES * HID_CH);
    unsigned short* h2b = (unsigned short*)alloc(sizeof(unsigned short) * (size_t)N_NODES * 64); // bf16 x 64ch

    if (used > ws_size) return;

    hipMemsetAsync(deg, 0, sizeof(int) * N_NODES, stream);
    k_count<<<FILL_NCHUNK * 8, 256, 0, stream>>>(ei, deg);
    ks1<<<NBLK, 256, 0, stream>>>(deg, rowptr, bsum);
    ks2<<<1, 512, 0, stream>>>(bsum, rowptr);
    ks3<<<NBLK, 256, 0, stream>>>(deg, rowptr, cursor, dinv, bsum);
    k_fill<<<FILL_NCHUNK * 8, 256, 0, stream>>>(ei, cursor, srcs);

    k_gemm<128, 8, 1><<<(N_NODES + 63) / 64, 256, 0, stream>>>(x, W1, (void*)h1b, N_NODES);
    k_agg128bf<<<AGG_BLOCKS, 256, 0, stream>>>(h1b, rowptr, srcs, dinv, b1, agg1, 1);
    k_gemm<64, 4, 1><<<(N_NODES + 63) / 64, 256, 0, stream>>>(agg1, W2, (void*)h2b, N_NODES);
    k_agg64bf<<<AGG_BLOCKS, 256, 0, stream>>>(h2b, rowptr, srcs, dinv, b2, out, 0);
}